// Round 1
// baseline (4485.799 us; speedup 1.0000x reference)
//
#include <hip/hip_runtime.h>
#include <stdint.h>
#include <math.h>

typedef unsigned short u16;
typedef short short8 __attribute__((ext_vector_type(8)));
typedef float f32x4 __attribute__((ext_vector_type(4)));

typedef const __attribute__((address_space(1))) void* gptr_t;
typedef __attribute__((address_space(3))) void* lptr_t;

#define BQ 4
#define SQ 1024
#define DQ 1024
#define HQ 16
#define HDQ 64
#define LQ 8
#define VQ 50257
#define SCALE_Q 0.125f

__device__ __forceinline__ float bf2f(u16 u) {
    return __uint_as_float(((unsigned int)u) << 16);
}
__device__ __forceinline__ u16 f2bf(float f) {
    unsigned int u = __float_as_uint(f);
    unsigned int r = u + 0x7fffu + ((u >> 16) & 1u);
    return (u16)(r >> 16);
}

// ---------------------------------------------------------------- embed
__global__ __launch_bounds__(256) void embed_kernel(
    const int* __restrict__ tok, const float* __restrict__ wte,
    const float* __restrict__ wpe, float* __restrict__ x)
{
    int row = blockIdx.x;            // 0..4095 = b*1024+s
    int s = row & 1023;
    int t = tok[row];
    int c = threadIdx.x * 4;
    float4 a = *(const float4*)(wte + (size_t)t * DQ + c);
    float4 p = *(const float4*)(wpe + (size_t)s * DQ + c);
    float4 o; o.x = a.x + p.x; o.y = a.y + p.y; o.z = a.z + p.z; o.w = a.w + p.w;
    *(float4*)(x + (size_t)row * DQ + c) = o;
}

// ---------------------------------------------------------------- layernorm (fp32 in, bf16 out)
__global__ __launch_bounds__(256) void ln_kernel(
    const float* __restrict__ x, u16* __restrict__ out,
    const float* __restrict__ g, const float* __restrict__ bta,
    long xstride, long ostride)
{
    int row = blockIdx.x;
    int tid = threadIdx.x;
    const float* xr = x + (size_t)row * xstride;
    float4 v = *(const float4*)(xr + tid * 4);
    float s = v.x + v.y + v.z + v.w;
    float q = v.x * v.x + v.y * v.y + v.z * v.z + v.w * v.w;
    for (int o = 32; o > 0; o >>= 1) { s += __shfl_down(s, o); q += __shfl_down(q, o); }
    __shared__ float red[8];
    __shared__ float mr[2];
    int lane = tid & 63, w = tid >> 6;
    if (!lane) { red[w] = s; red[4 + w] = q; }
    __syncthreads();
    if (!tid) {
        float ts = red[0] + red[1] + red[2] + red[3];
        float tq = red[4] + red[5] + red[6] + red[7];
        float m = ts * (1.0f / 1024.0f);
        float var = tq * (1.0f / 1024.0f) - m * m;
        mr[0] = m; mr[1] = rsqrtf(var + 1e-5f);
    }
    __syncthreads();
    float m = mr[0], r = mr[1];
    int c = tid * 4;
    float vv[4] = { v.x, v.y, v.z, v.w };
    u16* orow = out + (size_t)row * ostride;
    #pragma unroll
    for (int j = 0; j < 4; j++)
        orow[c + j] = f2bf((vv[j] - m) * r * g[c + j] + bta[c + j]);
}

// ---------------------------------------------------------------- weight transpose fp32 [R][C] -> bf16 [C][R]
__global__ __launch_bounds__(256) void transpose_w(
    const float* __restrict__ src, u16* __restrict__ dst, int R, int C)
{
    __shared__ float t[32][33];
    int c0 = blockIdx.x * 32, r0 = blockIdx.y * 32;
    int tx = threadIdx.x & 31, ty = threadIdx.x >> 5;
    #pragma unroll
    for (int i = 0; i < 4; i++) {
        int r = r0 + ty + i * 8;
        t[ty + i * 8][tx] = src[(size_t)r * C + c0 + tx];
    }
    __syncthreads();
    #pragma unroll
    for (int i = 0; i < 4; i++) {
        int c = c0 + ty + i * 8;
        dst[(size_t)c * R + r0 + tx] = f2bf(t[tx][ty + i * 8]);
    }
}

// ---------------------------------------------------------------- V transpose: qkv[b][s][2048+h*64+d] -> VT[bh][d][s]
__global__ __launch_bounds__(256) void v_transpose(
    const u16* __restrict__ qkv, u16* __restrict__ VT)
{
    int bh = blockIdx.y; int b = bh >> 4, h = bh & 15;
    int s0 = blockIdx.x * 64;
    __shared__ u16 t[64][65];
    int tid = threadIdx.x;
    #pragma unroll
    for (int i = 0; i < 16; i++) {
        int idx = tid + i * 256;
        int s = idx >> 6, d = idx & 63;
        t[s][d] = qkv[((size_t)(b * SQ + s0 + s)) * 3072 + 2048 + h * 64 + d];
    }
    __syncthreads();
    #pragma unroll
    for (int i = 0; i < 16; i++) {
        int idx = tid + i * 256;
        int d = idx >> 6, s = idx & 63;
        VT[((size_t)bh * 128 + d) * SQ + s0 + s] = t[s][d];
    }
}

// zero the pad rows d=64..127 of VT (once per call)
__global__ __launch_bounds__(256) void vt_padfill(u16* __restrict__ VT)
{
    int i = blockIdx.x * 256 + threadIdx.x;   // 64 bh * 65536
    int bh = i >> 16, off = i & 65535;
    VT[(size_t)bh * 131072 + 65536 + off] = 0;
}

// ---------------------------------------------------------------- causal softmax over bf16 scores, in place
__global__ __launch_bounds__(256) void softmax_causal(u16* __restrict__ sc)
{
    const long row = blockIdx.x;          // bh*1024 + q
    const int q = (int)(row & 1023);
    u16* pr = sc + row * 1024;
    const int tid = threadIdx.x;
    float v[4]; bool val[4];
    #pragma unroll
    for (int j = 0; j < 4; j++) {
        int c = tid + j * 256;
        val[j] = (c <= q);
        float f = bf2f(pr[c]);
        v[j] = val[j] ? f : -3.0e38f;
    }
    float m = fmaxf(fmaxf(v[0], v[1]), fmaxf(v[2], v[3]));
    for (int o = 32; o > 0; o >>= 1) m = fmaxf(m, __shfl_down(m, o));
    __shared__ float red[8];
    __shared__ float bc[2];
    int lane = tid & 63, w = tid >> 6;
    if (!lane) red[w] = m;
    __syncthreads();
    if (!tid) bc[0] = fmaxf(fmaxf(red[0], red[1]), fmaxf(red[2], red[3]));
    __syncthreads();
    m = bc[0];
    float e[4]; float s = 0.f;
    #pragma unroll
    for (int j = 0; j < 4; j++) { e[j] = val[j] ? __expf(v[j] - m) : 0.f; s += e[j]; }
    for (int o = 32; o > 0; o >>= 1) s += __shfl_down(s, o);
    if (!lane) red[w] = s;
    __syncthreads();
    if (!tid) bc[1] = red[0] + red[1] + red[2] + red[3];
    __syncthreads();
    float inv = 1.0f / bc[1];
    #pragma unroll
    for (int j = 0; j < 4; j++) pr[tid + j * 256] = f2bf(e[j] * inv);
}

// ---------------------------------------------------------------- GEMM: C[M,N] = A[M,K](bf16) * Bt[N,K](bf16)^T
// MODE 0: bf16 out = alpha*acc + bias  (bias nullable)
// MODE 1: bf16 out = gelu(acc + bias)
// MODE 2: fp32 out += acc + bias      (residual accumulate)
template<int MODE>
__global__ __launch_bounds__(256) void gemm128(
    const u16* __restrict__ A, const u16* __restrict__ Bt, void* __restrict__ Cv,
    const float* __restrict__ bias, int K, int lda, int ldb, int ldc,
    int Nvalid, float alpha, int innerB,
    long sAo, long sAi, long sBo, long sBi, long sCo, long sCi)
{
    __shared__ char smem[16384];          // As [128][32] bf16 | Bs [128][32] bf16
    const int tid = threadIdx.x;
    const int lane = tid & 63;
    const int wave = tid >> 6;
    const int wm = wave >> 1, wn = wave & 1;

    const int z = blockIdx.z;
    const long zo = z / innerB, zi = z % innerB;
    A += zo * sAo + zi * sAi;
    Bt += zo * sBo + zi * sBi;
    const long coff = zo * sCo + zi * sCi;

    const int m0 = blockIdx.y * 128, n0 = blockIdx.x * 128;

    const int r0 = tid >> 2, c0 = (tid & 3) * 8;     // chunk tid
    const int r1 = r0 + 64;                          // chunk tid+256
    char* ldsA0 = smem + wave * 1024;
    char* ldsA1 = smem + 4096 + wave * 1024;
    char* ldsB0 = smem + 8192 + wave * 1024;
    char* ldsB1 = smem + 8192 + 4096 + wave * 1024;

    f32x4 acc[16];
    f32x4 zero = { 0.f, 0.f, 0.f, 0.f };
    #pragma unroll
    for (int i = 0; i < 16; i++) acc[i] = zero;

    int aoff[4], boff[4];
    #pragma unroll
    for (int t = 0; t < 4; t++) {
        aoff[t] = ((wm * 64 + t * 16 + (lane & 15)) * 32 + (lane >> 4) * 8) * 2;
        boff[t] = 8192 + ((wn * 64 + t * 16 + (lane & 15)) * 32 + (lane >> 4) * 8) * 2;
    }

    for (int k0 = 0; k0 < K; k0 += 32) {
        __syncthreads();
        const u16* ga0 = A + (size_t)(m0 + r0) * lda + k0 + c0;
        const u16* ga1 = A + (size_t)(m0 + r1) * lda + k0 + c0;
        const u16* gb0 = Bt + (size_t)(n0 + r0) * ldb + k0 + c0;
        const u16* gb1 = Bt + (size_t)(n0 + r1) * ldb + k0 + c0;
        __builtin_amdgcn_global_load_lds((gptr_t)ga0, (lptr_t)ldsA0, 16, 0, 0);
        __builtin_amdgcn_global_load_lds((gptr_t)ga1, (lptr_t)ldsA1, 16, 0, 0);
        __builtin_amdgcn_global_load_lds((gptr_t)gb0, (lptr_t)ldsB0, 16, 0, 0);
        __builtin_amdgcn_global_load_lds((gptr_t)gb1, (lptr_t)ldsB1, 16, 0, 0);
        asm volatile("s_waitcnt vmcnt(0)" ::: "memory");
        __syncthreads();
        short8 af[4], bfr[4];
        #pragma unroll
        for (int t = 0; t < 4; t++) {
            af[t] = *(const short8*)(smem + aoff[t]);
            bfr[t] = *(const short8*)(smem + boff[t]);
        }
        #pragma unroll
        for (int mt = 0; mt < 4; mt++)
            #pragma unroll
            for (int nt = 0; nt < 4; nt++)
                acc[mt * 4 + nt] = __builtin_amdgcn_mfma_f32_16x16x32_bf16(
                    af[mt], bfr[nt], acc[mt * 4 + nt], 0, 0, 0);
    }

    const int cn = lane & 15, rq = lane >> 4;
    #pragma unroll
    for (int mt = 0; mt < 4; mt++) {
        #pragma unroll
        for (int nt = 0; nt < 4; nt++) {
            #pragma unroll
            for (int r = 0; r < 4; r++) {
                int m = m0 + wm * 64 + mt * 16 + rq * 4 + r;
                int n = n0 + wn * 64 + nt * 16 + cn;
                if (n < Nvalid) {
                    float v = acc[mt * 4 + nt][r] * alpha + (bias ? bias[n] : 0.f);
                    if (MODE == 1) v = 0.5f * v * (1.0f + erff(v * 0.70710678118654752f));
                    if (MODE == 2) {
                        float* C = (float*)Cv + coff;
                        C[(size_t)m * ldc + n] += v;
                    } else {
                        u16* C = (u16*)Cv + coff;
                        C[(size_t)m * ldc + n] = f2bf(v);
                    }
                }
            }
        }
    }
}

// ---------------------------------------------------------------- head: out[b][v] = xf[b][:] . w_head[:, v]
__global__ __launch_bounds__(256) void head_kernel(
    const u16* __restrict__ xf, const float* __restrict__ wh, float* __restrict__ out)
{
    __shared__ float xs[4 * 1024];
    int tid = threadIdx.x;
    #pragma unroll
    for (int i = 0; i < 16; i++) {
        int idx = tid + i * 256;
        xs[idx] = bf2f(xf[idx]);
    }
    __syncthreads();
    int v = blockIdx.x * 256 + tid;
    if (v >= VQ) return;
    float a0 = 0.f, a1 = 0.f, a2 = 0.f, a3 = 0.f;
    for (int k = 0; k < 1024; k++) {
        float w = wh[(size_t)k * VQ + v];
        a0 += xs[k] * w;
        a1 += xs[1024 + k] * w;
        a2 += xs[2048 + k] * w;
        a3 += xs[3072 + k] * w;
    }
    out[v] = a0;
    out[VQ + v] = a1;
    out[2 * (size_t)VQ + v] = a2;
    out[3 * (size_t)VQ + v] = a3;
}

// ================================================================ host
extern "C" void kernel_launch(void* const* d_in, const int* in_sizes, int n_in,
                              void* d_out, int out_size, void* d_ws, size_t ws_size,
                              hipStream_t stream)
{
    const int*   tokens = (const int*)d_in[0];
    const float* wte  = (const float*)d_in[1];
    const float* wpe  = (const float*)d_in[2];
    const float* ln1g = (const float*)d_in[3];
    const float* ln1b = (const float*)d_in[4];
    const float* wqkv = (const float*)d_in[5];
    const float* bqkv = (const float*)d_in[6];
    const float* wo   = (const float*)d_in[7];
    const float* bo   = (const float*)d_in[8];
    const float* ln2g = (const float*)d_in[9];
    const float* ln2b = (const float*)d_in[10];
    const float* w1   = (const float*)d_in[11];
    const float* b1   = (const float*)d_in[12];
    const float* w2   = (const float*)d_in[13];
    const float* b2   = (const float*)d_in[14];
    const float* lnfg = (const float*)d_in[15];
    const float* lnfb = (const float*)d_in[16];
    const float* whead= (const float*)d_in[17];
    float* out = (float*)d_out;

    uint8_t* p = (uint8_t*)d_ws;
    u16*  wqkvT = (u16*)p;  p += (size_t)3072 * 1024 * 2;
    u16*  woT   = (u16*)p;  p += (size_t)1024 * 1024 * 2;
    u16*  w1T   = (u16*)p;  p += (size_t)4096 * 1024 * 2;
    u16*  w2T   = (u16*)p;  p += (size_t)1024 * 4096 * 2;
    float* x    = (float*)p; p += (size_t)4096 * 1024 * 4;
    u16*  h     = (u16*)p;  p += (size_t)4096 * 1024 * 2;
    u16*  qkv   = (u16*)p;  p += (size_t)4096 * 3072 * 2;
    u16*  VT    = (u16*)p;  p += (size_t)64 * 128 * 1024 * 2;
    u16*  sc    = (u16*)p;  p += (size_t)64 * 1024 * 1024 * 2;
    u16*  attn  = (u16*)p;  p += (size_t)4096 * 1024 * 2;
    u16*  hid   = (u16*)p;  p += (size_t)4096 * 4096 * 2;
    u16*  xf    = (u16*)p;  p += (size_t)4096 * 2;

    embed_kernel<<<4096, 256, 0, stream>>>(tokens, wte, wpe, x);
    vt_padfill<<<16384, 256, 0, stream>>>(VT);

    for (int l = 0; l < LQ; l++) {
        // ---- attention
        ln_kernel<<<4096, 256, 0, stream>>>(x, h, ln1g + l * 1024, ln1b + l * 1024, 1024, 1024);
        transpose_w<<<dim3(96, 32), 256, 0, stream>>>(wqkv + (size_t)l * 1024 * 3072, wqkvT, 1024, 3072);
        // qkv = h @ Wqkv + b : M=4096 N=3072 K=1024
        gemm128<0><<<dim3(24, 32, 1), 256, 0, stream>>>(h, wqkvT, qkv, bqkv + l * 3072,
            1024, 1024, 1024, 3072, 3072, 1.0f, 1, 0, 0, 0, 0, 0, 0);
        v_transpose<<<dim3(16, 64), 256, 0, stream>>>(qkv, VT);
        // scores = SCALE * Q K^T : per (b,h), M=N=1024, K=64
        gemm128<0><<<dim3(8, 8, 64), 256, 0, stream>>>(qkv, qkv + 1024, sc, (const float*)nullptr,
            64, 3072, 3072, 1024, 1024, SCALE_Q, 16,
            (long)3145728, 64, (long)3145728, 64, (long)16777216, (long)1048576);
        softmax_causal<<<65536, 256, 0, stream>>>(sc);
        // O = P V : per (b,h), M=1024, N=128(pad), K=1024, store n<64 into attn[b][s][h*64+d]
        gemm128<0><<<dim3(1, 8, 64), 256, 0, stream>>>(sc, VT, attn, (const float*)nullptr,
            1024, 1024, 1024, 1024, 64, 1.0f, 16,
            (long)16777216, (long)1048576, (long)2097152, (long)131072, (long)1048576, 64);
        transpose_w<<<dim3(32, 32), 256, 0, stream>>>(wo + (size_t)l * 1024 * 1024, woT, 1024, 1024);
        // x += attn @ Wo + bo : M=4096 N=1024 K=1024, fp32 residual
        gemm128<2><<<dim3(8, 32, 1), 256, 0, stream>>>(attn, woT, x, bo + l * 1024,
            1024, 1024, 1024, 1024, 1024, 1.0f, 1, 0, 0, 0, 0, 0, 0);
        // ---- mlp
        ln_kernel<<<4096, 256, 0, stream>>>(x, h, ln2g + l * 1024, ln2b + l * 1024, 1024, 1024);
        transpose_w<<<dim3(128, 32), 256, 0, stream>>>(w1 + (size_t)l * 1024 * 4096, w1T, 1024, 4096);
        // hid = gelu(h @ W1 + b1) : M=4096 N=4096 K=1024
        gemm128<1><<<dim3(32, 32, 1), 256, 0, stream>>>(h, w1T, hid, b1 + l * 4096,
            1024, 1024, 1024, 4096, 4096, 1.0f, 1, 0, 0, 0, 0, 0, 0);
        transpose_w<<<dim3(32, 128), 256, 0, stream>>>(w2 + (size_t)l * 4096 * 1024, w2T, 4096, 1024);
        // x += hid @ W2 + b2 : M=4096 N=1024 K=4096, fp32 residual
        gemm128<2><<<dim3(8, 32, 1), 256, 0, stream>>>(hid, w2T, x, b2 + l * 1024,
            4096, 4096, 4096, 1024, 1024, 1.0f, 1, 0, 0, 0, 0, 0, 0);
    }

    // final LN on the 4 last-token rows, then head
    ln_kernel<<<4, 256, 0, stream>>>(x + (size_t)1023 * 1024, xf, lnfg, lnfb, 1048576, 1024);
    head_kernel<<<197, 256, 0, stream>>>(xf, whead, out);
}

// Round 2
// 3490.512 us; speedup vs baseline: 1.2851x; 1.2851x over previous
//
#include <hip/hip_runtime.h>
#include <stdint.h>
#include <math.h>

typedef unsigned short u16;
typedef short short8 __attribute__((ext_vector_type(8)));
typedef float f32x4 __attribute__((ext_vector_type(4)));

typedef const __attribute__((address_space(1))) void* gptr_t;
typedef __attribute__((address_space(3))) void* lptr_t;

#define BQ 4
#define SQ 1024
#define DQ 1024
#define HQ 16
#define HDQ 64
#define LQ 8
#define VQ 50257
#define SCALE_Q 0.125f

__device__ __forceinline__ float bf2f(u16 u) {
    return __uint_as_float(((unsigned int)u) << 16);
}
__device__ __forceinline__ u16 f2bf(float f) {
    unsigned int u = __float_as_uint(f);
    unsigned int r = u + 0x7fffu + ((u >> 16) & 1u);
    return (u16)(r >> 16);
}

// ---------------------------------------------------------------- embed
__global__ __launch_bounds__(256) void embed_kernel(
    const int* __restrict__ tok, const float* __restrict__ wte,
    const float* __restrict__ wpe, float* __restrict__ x)
{
    int row = blockIdx.x;            // 0..4095 = b*1024+s
    int s = row & 1023;
    int t = tok[row];
    int c = threadIdx.x * 4;
    float4 a = *(const float4*)(wte + (size_t)t * DQ + c);
    float4 p = *(const float4*)(wpe + (size_t)s * DQ + c);
    float4 o; o.x = a.x + p.x; o.y = a.y + p.y; o.z = a.z + p.z; o.w = a.w + p.w;
    *(float4*)(x + (size_t)row * DQ + c) = o;
}

// ---------------------------------------------------------------- layernorm (fp32 in, bf16 out)
__global__ __launch_bounds__(256) void ln_kernel(
    const float* __restrict__ x, u16* __restrict__ out,
    const float* __restrict__ g, const float* __restrict__ bta,
    long xstride, long ostride)
{
    int row = blockIdx.x;
    int tid = threadIdx.x;
    const float* xr = x + (size_t)row * xstride;
    float4 v = *(const float4*)(xr + tid * 4);
    float s = v.x + v.y + v.z + v.w;
    float q = v.x * v.x + v.y * v.y + v.z * v.z + v.w * v.w;
    for (int o = 32; o > 0; o >>= 1) { s += __shfl_down(s, o); q += __shfl_down(q, o); }
    __shared__ float red[8];
    __shared__ float mr[2];
    int lane = tid & 63, w = tid >> 6;
    if (!lane) { red[w] = s; red[4 + w] = q; }
    __syncthreads();
    if (!tid) {
        float ts = red[0] + red[1] + red[2] + red[3];
        float tq = red[4] + red[5] + red[6] + red[7];
        float m = ts * (1.0f / 1024.0f);
        float var = tq * (1.0f / 1024.0f) - m * m;
        mr[0] = m; mr[1] = rsqrtf(var + 1e-5f);
    }
    __syncthreads();
    float m = mr[0], r = mr[1];
    int c = tid * 4;
    float vv[4] = { v.x, v.y, v.z, v.w };
    u16* orow = out + (size_t)row * ostride;
    #pragma unroll
    for (int j = 0; j < 4; j++)
        orow[c + j] = f2bf((vv[j] - m) * r * g[c + j] + bta[c + j]);
}

// ---------------------------------------------------------------- weight transpose fp32 [R][C] -> bf16 [C][R]
__global__ __launch_bounds__(256) void transpose_w(
    const float* __restrict__ src, u16* __restrict__ dst, int R, int C)
{
    __shared__ float t[32][33];
    int c0 = blockIdx.x * 32, r0 = blockIdx.y * 32;
    int tx = threadIdx.x & 31, ty = threadIdx.x >> 5;
    #pragma unroll
    for (int i = 0; i < 4; i++) {
        int r = r0 + ty + i * 8;
        t[ty + i * 8][tx] = src[(size_t)r * C + c0 + tx];
    }
    __syncthreads();
    #pragma unroll
    for (int i = 0; i < 4; i++) {
        int c = c0 + ty + i * 8;
        dst[(size_t)c * R + r0 + tx] = f2bf(t[tx][ty + i * 8]);
    }
}

// ---------------------------------------------------------------- V transpose: qkv[b][s][2048+h*64+d] -> VT[bh][d][s]  (64 d-rows)
__global__ __launch_bounds__(256) void v_transpose(
    const u16* __restrict__ qkv, u16* __restrict__ VT)
{
    int bh = blockIdx.y; int b = bh >> 4, h = bh & 15;
    int s0 = blockIdx.x * 64;
    __shared__ u16 t[64][65];
    int tid = threadIdx.x;
    #pragma unroll
    for (int i = 0; i < 16; i++) {
        int idx = tid + i * 256;
        int s = idx >> 6, d = idx & 63;
        t[s][d] = qkv[((size_t)(b * SQ + s0 + s)) * 3072 + 2048 + h * 64 + d];
    }
    __syncthreads();
    #pragma unroll
    for (int i = 0; i < 16; i++) {
        int idx = tid + i * 256;
        int d = idx >> 6, s = idx & 63;
        VT[((size_t)bh * 64 + d) * SQ + s0 + s] = t[s][d];
    }
}

// ---------------------------------------------------------------- fused flash attention
// One block per (bh, q-tile of 128). Online softmax. O computed TRANSPOSED
// (O^T[d][q] = VT[d][ks] x P^T) so both MFMA operands read LDS rows
// contiguously. P tile is XOR-swizzled (chunk ^ q&15) to kill bank conflicts.
__global__ __launch_bounds__(256, 2) void flash_attn(
    const u16* __restrict__ qkv, const u16* __restrict__ VT, u16* __restrict__ attn)
{
    __shared__ char smem[65536];
    char* Pb = smem;              // 32 KB: swizzled P tile [128 q][256B]; Q tile at start
    char* Kb = smem + 32768;      // 16 KB: K tile [128 ks][128B]
    char* Vb = smem + 49152;      // 16 KB: VT tile [64 d][256B]
    float* abuf = (float*)Kb;     // 512 B alias — written only after K consumed

    const int tid = threadIdx.x;
    const int l = tid & 63, w = tid >> 6;
    const int lhi = l >> 4, llo = l & 15;
    const int bh = blockIdx.x; const int b = bh >> 4, h = bh & 15;
    const int qt = blockIdx.y;
    const int q0g = qt * 128;

    // stage this wave's own Q rows [w*32, w*32+32) into Pb (rows of 128 B)
    #pragma unroll
    for (int i = 0; i < 4; i++) {
        int off = (w * 4 + i) * 1024 + l * 16;
        int q = off >> 7, db = (off & 127) >> 1;
        const u16* g = qkv + (size_t)(b * 1024 + q0g + q) * 3072 + h * 64 + db;
        __builtin_amdgcn_global_load_lds((gptr_t)g, (lptr_t)(Pb + (w * 4 + i) * 1024), 16, 0, 0);
    }
    asm volatile("s_waitcnt vmcnt(0)" ::: "memory");

    short8 qf[2][2];                       // A-frags: 2 m-tiles x 2 k-steps
    #pragma unroll
    for (int mt = 0; mt < 2; mt++)
        #pragma unroll
        for (int ks = 0; ks < 2; ks++)
            qf[mt][ks] = *(const short8*)(Pb + (w * 32 + mt * 16 + llo) * 128 + (ks * 32 + lhi * 8) * 2);

    f32x4 oacc[4][2];                      // O^T accum: [d-mtile][q-ntile]
    f32x4 zero = { 0.f, 0.f, 0.f, 0.f };
    #pragma unroll
    for (int i = 0; i < 4; i++) { oacc[i][0] = zero; oacc[i][1] = zero; }
    float mrow[2][4], lrow[2][4];
    #pragma unroll
    for (int mt = 0; mt < 2; mt++)
        #pragma unroll
        for (int r = 0; r < 4; r++) { mrow[mt][r] = -1e30f; lrow[mt][r] = 0.f; }

    for (int kt = 0; kt <= qt; kt++) {
        const int kt0 = kt * 128;
        __syncthreads();                   // prev iter's K/VT reads done
        #pragma unroll
        for (int i = 0; i < 4; i++) {
            int off = (w * 4 + i) * 1024 + l * 16;
            int ks = off >> 7, db = (off & 127) >> 1;
            const u16* g = qkv + (size_t)(b * 1024 + kt0 + ks) * 3072 + 1024 + h * 64 + db;
            __builtin_amdgcn_global_load_lds((gptr_t)g, (lptr_t)(Kb + (w * 4 + i) * 1024), 16, 0, 0);
        }
        #pragma unroll
        for (int i = 0; i < 4; i++) {
            int off = (w * 4 + i) * 1024 + l * 16;
            int d = off >> 8, kb = (off & 255) >> 1;
            const u16* g = VT + ((size_t)(bh * 64 + d)) * 1024 + kt0 + kb;
            __builtin_amdgcn_global_load_lds((gptr_t)g, (lptr_t)(Vb + (w * 4 + i) * 1024), 16, 0, 0);
        }
        asm volatile("s_waitcnt vmcnt(0)" ::: "memory");
        __syncthreads();

        // ---- S = Q K^T (raw, scale folded into exp) ----
        f32x4 s[2][8];
        #pragma unroll
        for (int mt = 0; mt < 2; mt++)
            #pragma unroll
            for (int nt = 0; nt < 8; nt++) s[mt][nt] = zero;
        #pragma unroll
        for (int kst = 0; kst < 2; kst++)
            #pragma unroll
            for (int nt = 0; nt < 8; nt++) {
                short8 kf = *(const short8*)(Kb + (nt * 16 + llo) * 128 + (kst * 32 + lhi * 8) * 2);
                s[0][nt] = __builtin_amdgcn_mfma_f32_16x16x32_bf16(qf[0][kst], kf, s[0][nt], 0, 0, 0);
                s[1][nt] = __builtin_amdgcn_mfma_f32_16x16x32_bf16(qf[1][kst], kf, s[1][nt], 0, 0, 0);
            }
        __syncthreads();                   // all waves done reading K; abuf alias now safe

        // ---- causal mask: only the diagonal tile (kt==qt, local q vs local ks) ----
        if (kt == qt) {
            #pragma unroll
            for (int mt = 0; mt < 2; mt++)
                #pragma unroll
                for (int nt = 0; nt < 8; nt++)
                    #pragma unroll
                    for (int r = 0; r < 4; r++) {
                        int qloc = w * 32 + mt * 16 + lhi * 4 + r;
                        int ksloc = nt * 16 + llo;
                        if (ksloc > qloc) s[mt][nt][r] = -1e30f;
                    }
        }

        // ---- online softmax (rows live in lanes sharing lhi; reduce over llo) ----
        #pragma unroll
        for (int mt = 0; mt < 2; mt++) {
            #pragma unroll
            for (int r = 0; r < 4; r++) {
                float v = s[mt][0][r];
                #pragma unroll
                for (int nt = 1; nt < 8; nt++) v = fmaxf(v, s[mt][nt][r]);
                v = fmaxf(v, __shfl_xor(v, 1));
                v = fmaxf(v, __shfl_xor(v, 2));
                v = fmaxf(v, __shfl_xor(v, 4));
                v = fmaxf(v, __shfl_xor(v, 8));
                float mn = fmaxf(mrow[mt][r], v);
                float alpha = __expf((mrow[mt][r] - mn) * SCALE_Q);
                mrow[mt][r] = mn;
                int qrow = w * 32 + mt * 16 + lhi * 4 + r;
                int qm = qrow & 15;
                float rs = 0.f;
                #pragma unroll
                for (int nt = 0; nt < 8; nt++) {
                    float p = __expf((s[mt][nt][r] - mn) * SCALE_Q);
                    rs += p;
                    int phys = (nt * 2 + (llo >> 3)) ^ qm;
                    *(u16*)(Pb + qrow * 256 + phys * 16 + (l & 7) * 2) = f2bf(p);
                }
                rs += __shfl_xor(rs, 1);
                rs += __shfl_xor(rs, 2);
                rs += __shfl_xor(rs, 4);
                rs += __shfl_xor(rs, 8);
                lrow[mt][r] = lrow[mt][r] * alpha + rs;
                if (llo == 0) abuf[w * 32 + mt * 16 + lhi * 4 + r] = alpha;
            }
        }

        // ---- rescale O^T by alpha (per q = llo column) ----
        float a0 = abuf[w * 32 + llo];
        float a1 = abuf[w * 32 + 16 + llo];
        #pragma unroll
        for (int dmt = 0; dmt < 4; dmt++) { oacc[dmt][0] *= a0; oacc[dmt][1] *= a1; }

        // ---- O^T += VT x P^T : A-frag = VT rows (m=d), B-frag = P rows (n=q) ----
        #pragma unroll
        for (int kst = 0; kst < 4; kst++) {
            short8 pf[2];
            #pragma unroll
            for (int qnt = 0; qnt < 2; qnt++) {
                int q = w * 32 + qnt * 16 + llo;
                int phys = (kst * 4 + lhi) ^ (q & 15);
                pf[qnt] = *(const short8*)(Pb + q * 256 + phys * 16);
            }
            #pragma unroll
            for (int dmt = 0; dmt < 4; dmt++) {
                short8 vf = *(const short8*)(Vb + (dmt * 16 + llo) * 256 + (kst * 32 + lhi * 8) * 2);
                oacc[dmt][0] = __builtin_amdgcn_mfma_f32_16x16x32_bf16(vf, pf[0], oacc[dmt][0], 0, 0, 0);
                oacc[dmt][1] = __builtin_amdgcn_mfma_f32_16x16x32_bf16(vf, pf[1], oacc[dmt][1], 0, 0, 0);
            }
        }
    }

    // ---- epilogue: divide by l, store O[q][d] (O^T frag: col=q, 4 consecutive d) ----
    if (llo == 0) {
        #pragma unroll
        for (int mt = 0; mt < 2; mt++)
            #pragma unroll
            for (int r = 0; r < 4; r++)
                abuf[w * 32 + mt * 16 + lhi * 4 + r] = lrow[mt][r];
    }
    float li0 = 1.0f / abuf[w * 32 + llo];
    float li1 = 1.0f / abuf[w * 32 + 16 + llo];
    #pragma unroll
    for (int dmt = 0; dmt < 4; dmt++) {
        #pragma unroll
        for (int qnt = 0; qnt < 2; qnt++) {
            int q = q0g + w * 32 + qnt * 16 + llo;
            int d0 = dmt * 16 + lhi * 4;
            float li = qnt ? li1 : li0;
            u16 e0 = f2bf(oacc[dmt][qnt][0] * li);
            u16 e1 = f2bf(oacc[dmt][qnt][1] * li);
            u16 e2 = f2bf(oacc[dmt][qnt][2] * li);
            u16 e3 = f2bf(oacc[dmt][qnt][3] * li);
            uint2 pk;
            pk.x = (unsigned)e0 | ((unsigned)e1 << 16);
            pk.y = (unsigned)e2 | ((unsigned)e3 << 16);
            *(uint2*)(attn + (size_t)(b * 1024 + q) * 1024 + h * 64 + d0) = pk;
        }
    }
}

// ---------------------------------------------------------------- GEMM: C[M,N] = A[M,K](bf16) * Bt[N,K](bf16)^T
// MODE 0: bf16 out = alpha*acc + bias  (bias nullable)
// MODE 1: bf16 out = gelu(acc + bias)
// MODE 2: fp32 out += acc + bias      (residual accumulate)
// MODE 3: fp32 atomicAdd(out, acc [+ bias if zo==0])   (split-K residual)
template<int MODE>
__global__ __launch_bounds__(256) void gemm128(
    const u16* __restrict__ A, const u16* __restrict__ Bt, void* __restrict__ Cv,
    const float* __restrict__ bias, int K, int lda, int ldb, int ldc,
    int Nvalid, float alpha, int innerB,
    long sAo, long sAi, long sBo, long sBi, long sCo, long sCi)
{
    __shared__ char smem[16384];          // As [128][32] bf16 | Bs [128][32] bf16
    const int tid = threadIdx.x;
    const int lane = tid & 63;
    const int wave = tid >> 6;
    const int wm = wave >> 1, wn = wave & 1;

    const int z = blockIdx.z;
    const long zo = z / innerB, zi = z % innerB;
    A += zo * sAo + zi * sAi;
    Bt += zo * sBo + zi * sBi;
    const long coff = zo * sCo + zi * sCi;

    const int m0 = blockIdx.y * 128, n0 = blockIdx.x * 128;

    const int r0 = tid >> 2, c0 = (tid & 3) * 8;     // chunk tid
    const int r1 = r0 + 64;                          // chunk tid+256
    char* ldsA0 = smem + wave * 1024;
    char* ldsA1 = smem + 4096 + wave * 1024;
    char* ldsB0 = smem + 8192 + wave * 1024;
    char* ldsB1 = smem + 8192 + 4096 + wave * 1024;

    f32x4 acc[16];
    f32x4 zero = { 0.f, 0.f, 0.f, 0.f };
    #pragma unroll
    for (int i = 0; i < 16; i++) acc[i] = zero;

    int aoff[4], boff[4];
    #pragma unroll
    for (int t = 0; t < 4; t++) {
        aoff[t] = ((wm * 64 + t * 16 + (lane & 15)) * 32 + (lane >> 4) * 8) * 2;
        boff[t] = 8192 + ((wn * 64 + t * 16 + (lane & 15)) * 32 + (lane >> 4) * 8) * 2;
    }

    for (int k0 = 0; k0 < K; k0 += 32) {
        __syncthreads();
        const u16* ga0 = A + (size_t)(m0 + r0) * lda + k0 + c0;
        const u16* ga1 = A + (size_t)(m0 + r1) * lda + k0 + c0;
        const u16* gb0 = Bt + (size_t)(n0 + r0) * ldb + k0 + c0;
        const u16* gb1 = Bt + (size_t)(n0 + r1) * ldb + k0 + c0;
        __builtin_amdgcn_global_load_lds((gptr_t)ga0, (lptr_t)ldsA0, 16, 0, 0);
        __builtin_amdgcn_global_load_lds((gptr_t)ga1, (lptr_t)ldsA1, 16, 0, 0);
        __builtin_amdgcn_global_load_lds((gptr_t)gb0, (lptr_t)ldsB0, 16, 0, 0);
        __builtin_amdgcn_global_load_lds((gptr_t)gb1, (lptr_t)ldsB1, 16, 0, 0);
        asm volatile("s_waitcnt vmcnt(0)" ::: "memory");
        __syncthreads();
        short8 af[4], bfr[4];
        #pragma unroll
        for (int t = 0; t < 4; t++) {
            af[t] = *(const short8*)(smem + aoff[t]);
            bfr[t] = *(const short8*)(smem + boff[t]);
        }
        #pragma unroll
        for (int mt = 0; mt < 4; mt++)
            #pragma unroll
            for (int nt = 0; nt < 4; nt++)
                acc[mt * 4 + nt] = __builtin_amdgcn_mfma_f32_16x16x32_bf16(
                    af[mt], bfr[nt], acc[mt * 4 + nt], 0, 0, 0);
    }

    const int cn = lane & 15, rq = lane >> 4;
    #pragma unroll
    for (int mt = 0; mt < 4; mt++) {
        #pragma unroll
        for (int nt = 0; nt < 4; nt++) {
            #pragma unroll
            for (int r = 0; r < 4; r++) {
                int m = m0 + wm * 64 + mt * 16 + rq * 4 + r;
                int n = n0 + wn * 64 + nt * 16 + cn;
                if (n < Nvalid) {
                    float bv = (bias && (MODE != 3 || zo == 0)) ? bias[n] : 0.f;
                    float v = acc[mt * 4 + nt][r] * alpha + bv;
                    if (MODE == 1) v = 0.5f * v * (1.0f + erff(v * 0.70710678118654752f));
                    if (MODE == 2) {
                        float* C = (float*)Cv + coff;
                        C[(size_t)m * ldc + n] += v;
                    } else if (MODE == 3) {
                        float* C = (float*)Cv + coff;
                        atomicAdd(&C[(size_t)m * ldc + n], v);
                    } else {
                        u16* C = (u16*)Cv + coff;
                        C[(size_t)m * ldc + n] = f2bf(v);
                    }
                }
            }
        }
    }
}

// ---------------------------------------------------------------- head: out[b][v] = xf[b][:] . w_head[:, v]
__global__ __launch_bounds__(256) void head_kernel(
    const u16* __restrict__ xf, const float* __restrict__ wh, float* __restrict__ out)
{
    __shared__ float xs[4 * 1024];
    int tid = threadIdx.x;
    #pragma unroll
    for (int i = 0; i < 16; i++) {
        int idx = tid + i * 256;
        xs[idx] = bf2f(xf[idx]);
    }
    __syncthreads();
    int v = blockIdx.x * 256 + tid;
    if (v >= VQ) return;
    float a0 = 0.f, a1 = 0.f, a2 = 0.f, a3 = 0.f;
    for (int k = 0; k < 1024; k++) {
        float w = wh[(size_t)k * VQ + v];
        a0 += xs[k] * w;
        a1 += xs[1024 + k] * w;
        a2 += xs[2048 + k] * w;
        a3 += xs[3072 + k] * w;
    }
    out[v] = a0;
    out[VQ + v] = a1;
    out[2 * (size_t)VQ + v] = a2;
    out[3 * (size_t)VQ + v] = a3;
}

// ================================================================ host
extern "C" void kernel_launch(void* const* d_in, const int* in_sizes, int n_in,
                              void* d_out, int out_size, void* d_ws, size_t ws_size,
                              hipStream_t stream)
{
    const int*   tokens = (const int*)d_in[0];
    const float* wte  = (const float*)d_in[1];
    const float* wpe  = (const float*)d_in[2];
    const float* ln1g = (const float*)d_in[3];
    const float* ln1b = (const float*)d_in[4];
    const float* wqkv = (const float*)d_in[5];
    const float* bqkv = (const float*)d_in[6];
    const float* wo   = (const float*)d_in[7];
    const float* bo   = (const float*)d_in[8];
    const float* ln2g = (const float*)d_in[9];
    const float* ln2b = (const float*)d_in[10];
    const float* w1   = (const float*)d_in[11];
    const float* b1   = (const float*)d_in[12];
    const float* w2   = (const float*)d_in[13];
    const float* b2   = (const float*)d_in[14];
    const float* lnfg = (const float*)d_in[15];
    const float* lnfb = (const float*)d_in[16];
    const float* whead= (const float*)d_in[17];
    float* out = (float*)d_out;

    uint8_t* p = (uint8_t*)d_ws;
    u16*  wqkvT = (u16*)p;  p += (size_t)3072 * 1024 * 2;
    u16*  woT   = (u16*)p;  p += (size_t)1024 * 1024 * 2;
    u16*  w1T   = (u16*)p;  p += (size_t)4096 * 1024 * 2;
    u16*  w2T   = (u16*)p;  p += (size_t)1024 * 4096 * 2;
    float* x    = (float*)p; p += (size_t)4096 * 1024 * 4;
    u16*  h     = (u16*)p;  p += (size_t)4096 * 1024 * 2;
    u16*  qkv   = (u16*)p;  p += (size_t)4096 * 3072 * 2;
    u16*  VT    = (u16*)p;  p += (size_t)64 * 64 * 1024 * 2;
    u16*  attn  = (u16*)p;  p += (size_t)4096 * 1024 * 2;
    u16*  hid   = (u16*)p;  p += (size_t)4096 * 4096 * 2;
    u16*  xf    = (u16*)p;  p += (size_t)4096 * 2;

    embed_kernel<<<4096, 256, 0, stream>>>(tokens, wte, wpe, x);

    for (int l = 0; l < LQ; l++) {
        // ---- attention
        ln_kernel<<<4096, 256, 0, stream>>>(x, h, ln1g + l * 1024, ln1b + l * 1024, 1024, 1024);
        transpose_w<<<dim3(96, 32), 256, 0, stream>>>(wqkv + (size_t)l * 1024 * 3072, wqkvT, 1024, 3072);
        // qkv = h @ Wqkv + b : M=4096 N=3072 K=1024
        gemm128<0><<<dim3(24, 32, 1), 256, 0, stream>>>(h, wqkvT, qkv, bqkv + l * 3072,
            1024, 1024, 1024, 3072, 3072, 1.0f, 1, 0, 0, 0, 0, 0, 0);
        v_transpose<<<dim3(16, 64), 256, 0, stream>>>(qkv, VT);
        // fused flash attention -> attn[b][s][h*64+d]
        flash_attn<<<dim3(64, 8), 256, 0, stream>>>(qkv, VT, attn);
        transpose_w<<<dim3(32, 32), 256, 0, stream>>>(wo + (size_t)l * 1024 * 1024, woT, 1024, 1024);
        // x += attn @ Wo + bo : M=4096 N=1024 K=1024, fp32 residual
        gemm128<2><<<dim3(8, 32, 1), 256, 0, stream>>>(attn, woT, x, bo + l * 1024,
            1024, 1024, 1024, 1024, 1024, 1.0f, 1, 0, 0, 0, 0, 0, 0);
        // ---- mlp
        ln_kernel<<<4096, 256, 0, stream>>>(x, h, ln2g + l * 1024, ln2b + l * 1024, 1024, 1024);
        transpose_w<<<dim3(128, 32), 256, 0, stream>>>(w1 + (size_t)l * 1024 * 4096, w1T, 1024, 4096);
        // hid = gelu(h @ W1 + b1) : M=4096 N=4096 K=1024
        gemm128<1><<<dim3(32, 32, 1), 256, 0, stream>>>(h, w1T, hid, b1 + l * 4096,
            1024, 1024, 1024, 4096, 4096, 1.0f, 1, 0, 0, 0, 0, 0, 0);
        transpose_w<<<dim3(32, 128), 256, 0, stream>>>(w2 + (size_t)l * 4096 * 1024, w2T, 4096, 1024);
        // x += hid @ W2 + b2 : M=4096 N=1024 K=4096, split-K=2 fp32 atomic residual
        gemm128<3><<<dim3(8, 32, 2), 256, 0, stream>>>(hid, w2T, x, b2 + l * 1024,
            2048, 4096, 4096, 1024, 1024, 1.0f, 1, 2048, 0, 2048, 0, 0, 0);
    }

    // final LN on the 4 last-token rows, then head
    ln_kernel<<<4, 256, 0, stream>>>(x + (size_t)1023 * 1024, xf, lnfg, lnfb, 1048576, 1024);
    head_kernel<<<197, 256, 0, stream>>>(xf, whead, out);
}